// Round 4
// baseline (2021.576 us; speedup 1.0000x reference)
//
#include <hip/hip_runtime.h>
#include <stdint.h>
#include <math.h>

#define NB 16384  // batch

struct Ctrl {
  unsigned rank[4];
  unsigned key[4];
  float scale;
  unsigned pad[7];
  float lut[16];  // lut[i] = dequant value for nibble-index i, exact __fdiv_rn
};
static_assert(sizeof(Ctrl) == 128, "ctrl size");

__device__ __forceinline__ unsigned keyOf(float x) {
  unsigned u = __float_as_uint(x);
  return (u & 0x80000000u) ? ~u : (u | 0x80000000u);
}
__device__ __forceinline__ float keyToFloat(unsigned k) {
  unsigned u = (k & 0x80000000u) ? (k ^ 0x80000000u) : ~k;
  return __uint_as_float(u);
}
// dequant via LUT: floor/clamp then pick one of 16 exact s/scale values
__device__ __forceinline__ float qmapLut(float x, float scale, const float* lutS) {
  float t = __fmul_rn(x, scale);
  t = floorf(t);
  t = fminf(fmaxf(t, -128.0f), 127.0f);
  int qi = (int)t;
  return lutS[(qi >> 4) & 15];
}
__device__ __forceinline__ unsigned loadAgent(const unsigned* p) {
  return __hip_atomic_load(p, __ATOMIC_RELAXED, __HIP_MEMORY_SCOPE_AGENT);
}

// Wave-aggregated histogram add: one atomic per distinct bin among active lanes.
// Must be reached by all non-exec-masked lanes of the wave together.
__device__ __forceinline__ void histAddAgg(unsigned* h, unsigned bin, bool act) {
  unsigned long long todo = __ballot(act);
  unsigned lane = threadIdx.x & 63;
  while (todo) {
    unsigned lead = (unsigned)__builtin_ctzll(todo);
    unsigned lbin = (unsigned)__shfl((int)bin, (int)lead);
    bool m = act && (bin == lbin);
    unsigned long long mm = __ballot(m);
    if (lane == lead) atomicAdd(&h[lbin], (unsigned)__popcll(mm));
    todo &= ~mm;
  }
}

// Walks the (globally accumulated) histogram; refines rank/key for 4 targets.
// Called by all 256 threads of one block. base = scratch LDS (>=256 entries).
__device__ void scan_device(const unsigned* hist, int nbins, int sharedHist, int shift,
                            Ctrl* c, int first, unsigned r0, unsigned r1, unsigned r2,
                            unsigned r3, int finalize, float lwlo, float hwlo,
                            float lwhi, float hwhi, unsigned* base) {
  int t = threadIdx.x;
  unsigned rinit[4] = {r0, r1, r2, r3};
  int per = nbins / 256;
  for (int j = 0; j < 4; j++) {
    const unsigned* h = hist + (sharedHist ? 0 : j * nbins);
    unsigned s = 0;
    for (int i = 0; i < per; i++) s += loadAgent(&h[t * per + i]);
    base[t] = s;
    __syncthreads();
    if (t == 0) {
      unsigned acc = 0;
      for (int i = 0; i < 256; i++) { unsigned v = base[i]; base[i] = acc; acc += v; }
    }
    __syncthreads();
    unsigned rank = first ? rinit[j] : c->rank[j];
    unsigned bexc = base[t];
    if (rank >= bexc && rank < bexc + s) {
      unsigned cum = bexc;
      for (int i = 0; i < per; i++) {
        unsigned cnt = loadAgent(&h[t * per + i]);
        if (rank < cum + cnt) {
          c->rank[j] = rank - cum;
          c->key[j] |= ((unsigned)(t * per + i)) << shift;
          break;
        }
        cum += cnt;
      }
    }
    __syncthreads();
  }
  if (finalize) {
    if (t == 0) {
      float v0 = keyToFloat(c->key[0]), v1 = keyToFloat(c->key[1]);
      float v2 = keyToFloat(c->key[2]), v3 = keyToFloat(c->key[3]);
      float plo = __fadd_rn(__fmul_rn(v0, lwlo), __fmul_rn(v1, hwlo));
      float phi = __fadd_rn(__fmul_rn(v2, lwhi), __fmul_rn(v3, hwhi));
      float am = fmaxf(fabsf(plo), fabsf(phi));
      float sc = (am > 0.0f) ? __fdiv_rn(127.0f, am) : 128.0f;
      c->scale = sc;
      base[0] = __float_as_uint(sc);
    }
    __syncthreads();
    if (t < 16) {
      float sc = __uint_as_float(base[0]);
      int u2 = (t << 4) | 9;
      int s = (u2 >= 128) ? u2 - 256 : u2;
      c->lut[t] = __fdiv_rn((float)s, sc);
    }
  }
}

// ============ conv1 (1->6, 5x5, pad2) + relu + pool + hist-L1 + scan ============
// Post-ReLU values >= 0 so keyOf(v)>>20 >= 2048: LDS hist covers [2048,4096).
#define C1_IMGS 6
__global__ __launch_bounds__(256, 4) void conv1_fused(
    const float* __restrict__ x, const float* __restrict__ w,
    const float* __restrict__ bias, float* __restrict__ act1,
    unsigned* __restrict__ hist, unsigned* __restrict__ counter, Ctrl* ctrl,
    unsigned r0, unsigned r1, unsigned r2, unsigned r3) {
  __shared__ __align__(16) float img[C1_IMGS * 1032];  // 32x32 padded, stride 1032
  __shared__ float wl[150];
  __shared__ float bl[6];
  __shared__ unsigned h[2048];
  __shared__ unsigned lastFlag;
  int t = threadIdx.x;
  long long b0 = (long long)blockIdx.x * C1_IMGS;
  for (int i = t; i < 2048; i += 256) h[i] = 0;
  if (t < 150) wl[t] = w[t];
  if (t < 6) bl[t] = bias[t];
  for (int i = t; i < C1_IMGS * 1032; i += 256) img[i] = 0.0f;
  __syncthreads();
  for (int idx = t; idx < C1_IMGS * 784; idx += 256) {
    int im = idx / 784, rem = idx % 784;
    int r = rem / 28, cc = rem % 28;
    long long bb = b0 + im;
    if (bb < NB) img[im * 1032 + (r + 2) * 32 + (cc + 2)] = x[bb * 784 + rem];
  }
  __syncthreads();
  unsigned zc = 0;
  int im = t / 42, rem2 = t % 42, cg = rem2 / 14, pc = rem2 % 14;
  if (im < C1_IMGS) {
    long long bb = b0 + im;
    if (bb < NB) {
      const float* ib = &img[im * 1032];
      float wa[25], wb[25];
#pragma unroll
      for (int k = 0; k < 25; k++) {
        wa[k] = wl[(2 * cg) * 25 + k];
        wb[k] = wl[(2 * cg + 1) * 25 + k];
      }
      float biasA = bl[2 * cg], biasB = bl[2 * cg + 1];
      float* oA = act1 + bb * 1176 + (2 * cg) * 196 + pc;
      float* oB = oA + 196;
      for (int pr = 0; pr < 14; pr++) {
        float rw[6][6];
        const float* rp = ib + (2 * pr) * 32 + 2 * pc;
#pragma unroll
        for (int rr = 0; rr < 6; rr++) {
#pragma unroll
          for (int k2 = 0; k2 < 3; k2++) {
            float2 f = *(const float2*)&rp[rr * 32 + 2 * k2];
            rw[rr][2 * k2] = f.x;
            rw[rr][2 * k2 + 1] = f.y;
          }
        }
        float a00 = 0.f, a01 = 0.f, a10 = 0.f, a11 = 0.f;
        float c00 = 0.f, c01 = 0.f, c10 = 0.f, c11 = 0.f;
#pragma unroll
        for (int i = 0; i < 5; i++) {
#pragma unroll
          for (int j = 0; j < 5; j++) {
            float wva = wa[i * 5 + j], wvb = wb[i * 5 + j];
            a00 = fmaf(rw[i][j], wva, a00);
            a01 = fmaf(rw[i][j + 1], wva, a01);
            a10 = fmaf(rw[i + 1][j], wva, a10);
            a11 = fmaf(rw[i + 1][j + 1], wva, a11);
            c00 = fmaf(rw[i][j], wvb, c00);
            c01 = fmaf(rw[i][j + 1], wvb, c01);
            c10 = fmaf(rw[i + 1][j], wvb, c10);
            c11 = fmaf(rw[i + 1][j + 1], wvb, c11);
          }
        }
        float ma = fmaxf(fmaxf(a00, a01), fmaxf(a10, a11));
        float mb = fmaxf(fmaxf(c00, c01), fmaxf(c10, c11));
        float va = fmaxf(ma + biasA, 0.0f);
        float vb = fmaxf(mb + biasB, 0.0f);
        bool za = ((__float_as_uint(va) << 1) == 0u);
        bool zb = ((__float_as_uint(vb) << 1) == 0u);
        if (za) { zc++; va = 0.0f; }
        if (zb) { zc++; vb = 0.0f; }
        oA[pr * 14] = va;
        oB[pr * 14] = vb;
        histAddAgg(h, (keyOf(va) >> 20) - 2048, !za);
        histAddAgg(h, (keyOf(vb) >> 20) - 2048, !zb);
      }
    }
  }
  if (zc) atomicAdd(&h[0], zc);  // zero bin = key 2048
  __syncthreads();
  for (int i = t; i < 2048; i += 256) {
    unsigned v = h[i];
    if (v) atomicAdd(&hist[2048 + i], v);
  }
  __threadfence();
  if (t == 0) lastFlag = (atomicAdd(counter, 1u) == gridDim.x - 1);
  __syncthreads();
  if (lastFlag)
    scan_device(hist, 4096, 1, 20, ctrl, 1, r0, r1, r2, r3, 0, 0.f, 0.f, 0.f, 0.f, h);
}

// ===== conv2 (6->16, 5x5 VALID) + LUT-dequant + relu + pool + hist-L1 =====
#define C2_IMGS 10
__global__ __launch_bounds__(256, 2) void conv2_fused(
    const float* __restrict__ act1, const float* __restrict__ w,
    const float* __restrict__ bias, const Ctrl* __restrict__ cin,
    float* __restrict__ act2, unsigned* __restrict__ hist,
    unsigned* __restrict__ counter, Ctrl* ctrl,
    unsigned r0, unsigned r1, unsigned r2, unsigned r3) {
  __shared__ __align__(16) float img[C2_IMGS * 1176];  // linear copy of 10 images
  __shared__ __align__(16) float wl[3840];             // [c][ci][ki][8] padded rows
  __shared__ float bl[16];
  __shared__ float lutS[16];
  __shared__ unsigned h[2048];
  __shared__ unsigned lastFlag;
  int t = threadIdx.x;
  long long b0 = (long long)blockIdx.x * C2_IMGS;
  float scale = cin->scale;
  for (int i = t; i < 2048; i += 256) h[i] = 0;
  for (int idx = t; idx < 2400; idx += 256) {
    int c = idx / 150, rem = idx % 150;
    int ci = rem / 25, k = rem % 25;
    wl[((c * 6 + ci) * 5 + k / 5) * 8 + k % 5] = w[idx];
  }
  if (t < 16) { bl[t] = bias[t]; lutS[t] = cin->lut[t]; }
  __syncthreads();  // lutS ready before staging
  long long imgs = NB - b0;
  if (imgs > C2_IMGS) imgs = C2_IMGS;
  int nrem = (int)imgs * 1176;
  for (int idx = t; idx < C2_IMGS * 1176; idx += 256) {
    float v = 0.0f;
    if (idx < nrem) v = qmapLut(act1[b0 * 1176 + idx], scale, lutS);
    img[idx] = v;
  }
  __syncthreads();
  unsigned zc = 0;
  int im = t / 25, p = t % 25;  // t < 250 active
  if (im < C2_IMGS && b0 + im < NB) {
    long long bb = b0 + im;
    int pr = p / 5, pcol = p % 5;
    const float* ib = &img[im * 1176 + pr * 28 + 2 * pcol];
#pragma unroll
    for (int half = 0; half < 2; half++) {
      float acc[8][4];
#pragma unroll
      for (int cc = 0; cc < 8; cc++)
#pragma unroll
        for (int q = 0; q < 4; q++) acc[cc][q] = 0.f;
      for (int ci = 0; ci < 6; ci++) {
        float win[6][6];
        const float* rp = ib + ci * 196;
#pragma unroll
        for (int rr = 0; rr < 6; rr++) {
#pragma unroll
          for (int k2 = 0; k2 < 3; k2++) {
            float2 f = *(const float2*)&rp[rr * 14 + 2 * k2];
            win[rr][2 * k2] = f.x;
            win[rr][2 * k2 + 1] = f.y;
          }
        }
#pragma unroll
        for (int cc = 0; cc < 8; cc++) {
          int c = half * 8 + cc;
#pragma unroll
          for (int ki = 0; ki < 5; ki++) {
            const float* wr = &wl[((c * 6 + ci) * 5 + ki) * 8];
            float4 w0 = *(const float4*)wr;
            float wk[5] = {w0.x, w0.y, w0.z, w0.w, wr[4]};
#pragma unroll
            for (int kj = 0; kj < 5; kj++) {
              float wv = wk[kj];
              acc[cc][0] = fmaf(win[ki][kj], wv, acc[cc][0]);
              acc[cc][1] = fmaf(win[ki][kj + 1], wv, acc[cc][1]);
              acc[cc][2] = fmaf(win[ki + 1][kj], wv, acc[cc][2]);
              acc[cc][3] = fmaf(win[ki + 1][kj + 1], wv, acc[cc][3]);
            }
          }
        }
      }
#pragma unroll
      for (int cc = 0; cc < 8; cc++) {
        int c = half * 8 + cc;
        float m = fmaxf(fmaxf(acc[cc][0], acc[cc][1]), fmaxf(acc[cc][2], acc[cc][3]));
        float v = fmaxf(m + bl[c], 0.0f);
        bool z = ((__float_as_uint(v) << 1) == 0u);
        if (z) { zc++; v = 0.0f; }
        act2[(bb * 16 + c) * 25 + p] = v;
        histAddAgg(h, (keyOf(v) >> 20) - 2048, !z);
      }
    }
  }
  if (zc) atomicAdd(&h[0], zc);
  __syncthreads();
  for (int i = t; i < 2048; i += 256) {
    unsigned v = h[i];
    if (v) atomicAdd(&hist[2048 + i], v);
  }
  __threadfence();
  if (t == 0) lastFlag = (atomicAdd(counter, 1u) == gridDim.x - 1);
  __syncthreads();
  if (lastFlag)
    scan_device(hist, 4096, 1, 20, ctrl, 1, r0, r1, r2, r3, 0, 0.f, 0.f, 0.f, 0.f, h);
}

// ============ sub-level histogram pass + fused scan (levels 2 and 3) ============
__global__ __launch_bounds__(256) void sub_fused(
    const float4* __restrict__ a, long long n4, Ctrl* c,
    unsigned* __restrict__ histOut, int level, unsigned* __restrict__ counter,
    int finalize, float lwlo, float hwlo, float lwhi, float hwhi) {
  __shared__ unsigned h[4096];
  __shared__ unsigned lastFlag;
  int t = threadIdx.x;
  for (int i = t; i < 4096; i += 256) h[i] = 0;
  __syncthreads();
  unsigned p0 = c->key[0], p1 = c->key[1], p2 = c->key[2], p3 = c->key[3];
  unsigned mask = (level == 2) ? 0xFFF00000u : 0xFFFFFC00u;
  int sh = (level == 2) ? 10 : 0;
  const unsigned zkey = 0x80000000u;
  int zm0 = ((zkey & mask) == p0), zm1 = ((zkey & mask) == p1);
  int zm2 = ((zkey & mask) == p2), zm3 = ((zkey & mask) == p3);
  unsigned zbin = (zkey >> sh) & 1023u;
  unsigned zc = 0;
  long long stride = (long long)gridDim.x * 256;
  for (long long i = (long long)blockIdx.x * 256 + t; i < n4; i += stride) {
    float4 v = a[i];
    float vals[4] = {v.x, v.y, v.z, v.w};
#pragma unroll
    for (int q = 0; q < 4; q++) {
      unsigned bits = __float_as_uint(vals[q]);
      if (bits == 0u) { zc++; continue; }
      unsigned k = keyOf(vals[q]);
      unsigned pf = k & mask;
      unsigned bin = (k >> sh) & 1023u;
      if (pf == p0) atomicAdd(&h[bin], 1u);
      if (pf == p1) atomicAdd(&h[1024 + bin], 1u);
      if (pf == p2) atomicAdd(&h[2048 + bin], 1u);
      if (pf == p3) atomicAdd(&h[3072 + bin], 1u);
    }
  }
  if (zc) {
    if (zm0) atomicAdd(&h[zbin], zc);
    if (zm1) atomicAdd(&h[1024 + zbin], zc);
    if (zm2) atomicAdd(&h[2048 + zbin], zc);
    if (zm3) atomicAdd(&h[3072 + zbin], zc);
  }
  __syncthreads();
  for (int i = t; i < 4096; i += 256) {
    unsigned v = h[i];
    if (v) atomicAdd(&histOut[i], v);
  }
  __threadfence();
  if (t == 0) lastFlag = (atomicAdd(counter, 1u) == gridDim.x - 1);
  __syncthreads();
  if (lastFlag)
    scan_device(histOut, 1024, 0, sh, c, 0, 0u, 0u, 0u, 0u, finalize, lwlo, hwlo, lwhi, hwhi, h);
}

// ============ fc1: [B,400] x [120,400]^T + LUT-dequant + relu + hist ============
__global__ __launch_bounds__(256, 2) void fc1_fused(
    const float* __restrict__ A, const float* __restrict__ W,
    const float* __restrict__ bias, const Ctrl* __restrict__ cin,
    float* __restrict__ out, unsigned* __restrict__ hist,
    unsigned* __restrict__ counter, Ctrl* ctrl,
    unsigned r0, unsigned r1, unsigned r2, unsigned r3) {
  __shared__ float As[32][100];
  __shared__ float Ws[120][100];
  __shared__ float lutS[16];
  __shared__ unsigned h[2048];
  __shared__ unsigned lastFlag;
  int t = threadIdx.x;
  size_t b0 = (size_t)blockIdx.x * 32;
  float scale = cin->scale;
  for (int i = t; i < 2048; i += 256) h[i] = 0;
  if (t < 16) lutS[t] = cin->lut[t];
  int ng = t & 7, bs = t >> 3;
  float acc[15];
#pragma unroll
  for (int i = 0; i < 15; i++) acc[i] = 0.f;
  for (int kc = 0; kc < 4; kc++) {
    __syncthreads();
    for (int idx = t; idx < 3200; idx += 256) {
      int row = idx / 100, k = idx % 100;
      As[row][k] = qmapLut(A[(b0 + row) * 400 + kc * 100 + k], scale, lutS);
    }
    for (int idx = t; idx < 12000; idx += 256) {
      int n = idx / 100, k = idx % 100;
      Ws[n][k] = W[n * 400 + kc * 100 + k];
    }
    __syncthreads();
    for (int k = 0; k < 100; k++) {
      float av = As[bs][k];
#pragma unroll
      for (int i = 0; i < 15; i++) acc[i] = fmaf(av, Ws[ng + 8 * i][k], acc[i]);
    }
  }
  unsigned zc = 0;
#pragma unroll
  for (int i = 0; i < 15; i++) {
    int n = ng + 8 * i;
    float v = fmaxf(acc[i] + bias[n], 0.0f);
    bool z = ((__float_as_uint(v) << 1) == 0u);
    if (z) { zc++; v = 0.0f; }
    out[(b0 + bs) * 120 + n] = v;
    histAddAgg(h, (keyOf(v) >> 20) - 2048, !z);
  }
  if (zc) atomicAdd(&h[0], zc);
  __syncthreads();
  for (int i = t; i < 2048; i += 256) {
    unsigned v = h[i];
    if (v) atomicAdd(&hist[2048 + i], v);
  }
  __threadfence();
  if (t == 0) lastFlag = (atomicAdd(counter, 1u) == gridDim.x - 1);
  __syncthreads();
  if (lastFlag)
    scan_device(hist, 4096, 1, 20, ctrl, 1, r0, r1, r2, r3, 0, 0.f, 0.f, 0.f, 0.f, h);
}

// ============ fc2: [B,120] x [84,120]^T + LUT-dequant + relu + hist ============
__global__ __launch_bounds__(256, 2) void fc2_fused(
    const float* __restrict__ A, const float* __restrict__ W,
    const float* __restrict__ bias, const Ctrl* __restrict__ cin,
    float* __restrict__ out, unsigned* __restrict__ hist,
    unsigned* __restrict__ counter, Ctrl* ctrl,
    unsigned r0, unsigned r1, unsigned r2, unsigned r3) {
  __shared__ float As[64][121];
  __shared__ float Ws[84][120];
  __shared__ float lutS[16];
  __shared__ unsigned h[2048];
  __shared__ unsigned lastFlag;
  int t = threadIdx.x;
  size_t b0 = (size_t)blockIdx.x * 64;
  float scale = cin->scale;
  for (int i = t; i < 2048; i += 256) h[i] = 0;
  if (t < 16) lutS[t] = cin->lut[t];
  __syncthreads();  // lutS ready
  int ng = t & 3, bs = t >> 2;
  float acc[21];
#pragma unroll
  for (int i = 0; i < 21; i++) acc[i] = 0.f;
  for (int idx = t; idx < 7680; idx += 256) {
    int row = idx / 120, k = idx % 120;
    As[row][k] = qmapLut(A[(b0 + row) * 120 + k], scale, lutS);
  }
  for (int idx = t; idx < 10080; idx += 256) {
    int n = idx / 120, k = idx % 120;
    Ws[n][k] = W[n * 120 + k];
  }
  __syncthreads();
  for (int k = 0; k < 120; k++) {
    float av = As[bs][k];
#pragma unroll
    for (int i = 0; i < 21; i++) acc[i] = fmaf(av, Ws[ng + 4 * i][k], acc[i]);
  }
  unsigned zc = 0;
#pragma unroll
  for (int i = 0; i < 21; i++) {
    int n = ng + 4 * i;
    float v = fmaxf(acc[i] + bias[n], 0.0f);
    bool z = ((__float_as_uint(v) << 1) == 0u);
    if (z) { zc++; v = 0.0f; }
    out[(b0 + bs) * 84 + n] = v;
    histAddAgg(h, (keyOf(v) >> 20) - 2048, !z);
  }
  if (zc) atomicAdd(&h[0], zc);
  __syncthreads();
  for (int i = t; i < 2048; i += 256) {
    unsigned v = h[i];
    if (v) atomicAdd(&hist[2048 + i], v);
  }
  __threadfence();
  if (t == 0) lastFlag = (atomicAdd(counter, 1u) == gridDim.x - 1);
  __syncthreads();
  if (lastFlag)
    scan_device(hist, 4096, 1, 20, ctrl, 1, r0, r1, r2, r3, 0, 0.f, 0.f, 0.f, 0.f, h);
}

// ============ fc3: [B,84] x [10,84]^T + LUT-dequant -> d_out ============
__global__ __launch_bounds__(256) void fc3_fused(
    const float* __restrict__ A, const float* __restrict__ W,
    const float* __restrict__ bias, const Ctrl* __restrict__ cin,
    float* __restrict__ out) {
  __shared__ float As[64][84];
  __shared__ float Ws[10][84];
  __shared__ float bl[10];
  __shared__ float lutS[16];
  int t = threadIdx.x;
  size_t b0 = (size_t)blockIdx.x * 64;
  float scale = cin->scale;
  if (t < 16) lutS[t] = cin->lut[t];
  __syncthreads();  // lutS ready
  int ng = t & 3, bs = t >> 2;
  for (int idx = t; idx < 5376; idx += 256) {
    int row = idx / 84, k = idx % 84;
    As[row][k] = qmapLut(A[(b0 + row) * 84 + k], scale, lutS);
  }
  for (int idx = t; idx < 840; idx += 256) Ws[idx / 84][idx % 84] = W[idx];
  if (t < 10) bl[t] = bias[t];
  __syncthreads();
  float acc[3] = {0.f, 0.f, 0.f};
  for (int k = 0; k < 84; k++) {
    float av = As[bs][k];
#pragma unroll
    for (int i = 0; i < 3; i++) {
      int n = ng + 4 * i;
      if (n < 10) acc[i] = fmaf(av, Ws[n][k], acc[i]);
    }
  }
#pragma unroll
  for (int i = 0; i < 3; i++) {
    int n = ng + 4 * i;
    if (n < 10) out[(b0 + bs) * 10 + n] = acc[i] + bl[n];
  }
}

// ---------------- host ----------------
static void qparams(long long n, unsigned r[4], float w[4]) {
  float nf = (float)n;
  float nm1 = nf - 1.0f;
  float qlo = 2.5f / 100.0f, qhi = 97.5f / 100.0f;
  float ilo = qlo * nm1;
  float flo = floorf(ilo), clo = ceilf(ilo);
  float hwlo = ilo - flo, lwlo = 1.0f - hwlo;
  float ihi = qhi * nm1;
  float fhi = floorf(ihi), chi = ceilf(ihi);
  float hwhi = ihi - fhi, lwhi = 1.0f - hwhi;
  if (flo < 0) flo = 0;
  if (clo < 0) clo = 0;
  if (fhi < 0) fhi = 0;
  if (chi < 0) chi = 0;
  unsigned nmax = (unsigned)(n - 1);
  r[0] = (unsigned)flo; if (r[0] > nmax) r[0] = nmax;
  r[1] = (unsigned)clo; if (r[1] > nmax) r[1] = nmax;
  r[2] = (unsigned)fhi; if (r[2] > nmax) r[2] = nmax;
  r[3] = (unsigned)chi; if (r[3] > nmax) r[3] = nmax;
  w[0] = lwlo; w[1] = hwlo; w[2] = lwhi; w[3] = hwhi;
}

extern "C" void kernel_launch(void* const* d_in, const int* in_sizes, int n_in,
                              void* d_out, int out_size, void* d_ws, size_t ws_size,
                              hipStream_t stream) {
  const float* x   = (const float*)d_in[0];
  const float* c1w = (const float*)d_in[1];
  const float* c1b = (const float*)d_in[2];
  const float* c2w = (const float*)d_in[3];
  const float* c2b = (const float*)d_in[4];
  const float* f1w = (const float*)d_in[5];
  const float* f1b = (const float*)d_in[6];
  const float* f2w = (const float*)d_in[7];
  const float* f2b = (const float*)d_in[8];
  const float* f3w = (const float*)d_in[9];
  const float* f3b = (const float*)d_in[10];
  float* outp = (float*)d_out;

  char* ws = (char*)d_ws;
  size_t off = 0;
  auto alloc = [&](size_t bytes) {
    void* p = ws + off;
    off += (bytes + 255) & ~(size_t)255;
    return p;
  };
  float* act1 = (float*)alloc((size_t)NB * 1176 * 4);
  float* act2 = (float*)alloc((size_t)NB * 400 * 4);
  size_t metaBytes = 4 * 12288 * 4 + 16 * 4 + 4 * sizeof(Ctrl);
  unsigned* meta = (unsigned*)alloc(metaBytes);
  unsigned* cnt = meta + 4 * 12288;
  Ctrl* ctrl = (Ctrl*)(cnt + 16);
  float* fc1o = act1;                     // reuse after conv2 consumed act1
  float* fc2o = act1 + (size_t)NB * 120;

  auto H = [&](int s, int lvl) {  // lvl 1,2,3
    return meta + s * 12288 + (lvl == 1 ? 0 : (lvl == 2 ? 4096 : 8192));
  };

  long long n1 = (long long)NB * 1176, n2 = (long long)NB * 400;
  long long n3 = (long long)NB * 120, n4n = (long long)NB * 84;
  unsigned r1[4], r2[4], r3[4], r4[4];
  float w1[4], w2[4], w3[4], w4[4];
  qparams(n1, r1, w1);
  qparams(n2, r2, w2);
  qparams(n3, r3, w3);
  qparams(n4n, r4, w4);

  hipMemsetAsync(meta, 0, metaBytes, stream);

  int g1 = (NB + C1_IMGS - 1) / C1_IMGS;  // 2731
  int g2 = (NB + C2_IMGS - 1) / C2_IMGS;  // 1639

  conv1_fused<<<g1, 256, 0, stream>>>(x, c1w, c1b, act1, H(0, 1), &cnt[0], &ctrl[0],
                                      r1[0], r1[1], r1[2], r1[3]);
  sub_fused<<<2048, 256, 0, stream>>>((const float4*)act1, n1 / 4, &ctrl[0], H(0, 2), 2,
                                      &cnt[1], 0, 0.f, 0.f, 0.f, 0.f);
  sub_fused<<<2048, 256, 0, stream>>>((const float4*)act1, n1 / 4, &ctrl[0], H(0, 3), 3,
                                      &cnt[2], 1, w1[0], w1[1], w1[2], w1[3]);
  conv2_fused<<<g2, 256, 0, stream>>>(act1, c2w, c2b, &ctrl[0], act2, H(1, 1), &cnt[3],
                                      &ctrl[1], r2[0], r2[1], r2[2], r2[3]);
  sub_fused<<<2048, 256, 0, stream>>>((const float4*)act2, n2 / 4, &ctrl[1], H(1, 2), 2,
                                      &cnt[4], 0, 0.f, 0.f, 0.f, 0.f);
  sub_fused<<<2048, 256, 0, stream>>>((const float4*)act2, n2 / 4, &ctrl[1], H(1, 3), 3,
                                      &cnt[5], 1, w2[0], w2[1], w2[2], w2[3]);
  fc1_fused<<<NB / 32, 256, 0, stream>>>(act2, f1w, f1b, &ctrl[1], fc1o, H(2, 1), &cnt[6],
                                         &ctrl[2], r3[0], r3[1], r3[2], r3[3]);
  sub_fused<<<512, 256, 0, stream>>>((const float4*)fc1o, n3 / 4, &ctrl[2], H(2, 2), 2,
                                     &cnt[7], 0, 0.f, 0.f, 0.f, 0.f);
  sub_fused<<<512, 256, 0, stream>>>((const float4*)fc1o, n3 / 4, &ctrl[2], H(2, 3), 3,
                                     &cnt[8], 1, w3[0], w3[1], w3[2], w3[3]);
  fc2_fused<<<NB / 64, 256, 0, stream>>>(fc1o, f2w, f2b, &ctrl[2], fc2o, H(3, 1), &cnt[9],
                                         &ctrl[3], r4[0], r4[1], r4[2], r4[3]);
  sub_fused<<<512, 256, 0, stream>>>((const float4*)fc2o, n4n / 4, &ctrl[3], H(3, 2), 2,
                                     &cnt[10], 0, 0.f, 0.f, 0.f, 0.f);
  sub_fused<<<512, 256, 0, stream>>>((const float4*)fc2o, n4n / 4, &ctrl[3], H(3, 3), 3,
                                     &cnt[11], 1, w4[0], w4[1], w4[2], w4[3]);
  fc3_fused<<<NB / 64, 256, 0, stream>>>(fc2o, f3w, f3b, &ctrl[3], outp);
}

// Round 5
// 1433.757 us; speedup vs baseline: 1.4100x; 1.4100x over previous
//
#include <hip/hip_runtime.h>
#include <stdint.h>
#include <math.h>

#define NB 16384  // batch

struct Ctrl {
  unsigned rank[4];
  unsigned key[4];
  float scale;
  unsigned pad[7];
  float lut[16];  // lut[i] = dequant value for nibble-index i, exact __fdiv_rn
};
static_assert(sizeof(Ctrl) == 128, "ctrl size");

__device__ __forceinline__ unsigned keyOf(float x) {
  unsigned u = __float_as_uint(x);
  return (u & 0x80000000u) ? ~u : (u | 0x80000000u);
}
__device__ __forceinline__ float keyToFloat(unsigned k) {
  unsigned u = (k & 0x80000000u) ? (k ^ 0x80000000u) : ~k;
  return __uint_as_float(u);
}
// dequant via LUT: floor/clamp then pick one of 16 exact s/scale values
__device__ __forceinline__ float qmapLut(float x, float scale, const float* lutS) {
  float t = __fmul_rn(x, scale);
  t = floorf(t);
  t = fminf(fmaxf(t, -128.0f), 127.0f);
  int qi = (int)t;
  return lutS[(qi >> 4) & 15];
}
__device__ __forceinline__ unsigned loadAgent(const unsigned* p) {
  return __hip_atomic_load(p, __ATOMIC_RELAXED, __HIP_MEMORY_SCOPE_AGENT);
}

// Walks the (globally accumulated) histogram; refines rank/key for 4 targets.
// Called by all 256 threads of one block. base = scratch LDS (>=256 entries).
__device__ void scan_device(const unsigned* hist, int nbins, int sharedHist, int shift,
                            Ctrl* c, int first, unsigned r0, unsigned r1, unsigned r2,
                            unsigned r3, int finalize, float lwlo, float hwlo,
                            float lwhi, float hwhi, unsigned* base) {
  int t = threadIdx.x;
  unsigned rinit[4] = {r0, r1, r2, r3};
  int per = nbins / 256;
  for (int j = 0; j < 4; j++) {
    const unsigned* h = hist + (sharedHist ? 0 : j * nbins);
    unsigned s = 0;
    for (int i = 0; i < per; i++) s += loadAgent(&h[t * per + i]);
    base[t] = s;
    __syncthreads();
    if (t == 0) {
      unsigned acc = 0;
      for (int i = 0; i < 256; i++) { unsigned v = base[i]; base[i] = acc; acc += v; }
    }
    __syncthreads();
    unsigned rank = first ? rinit[j] : c->rank[j];
    unsigned bexc = base[t];
    if (rank >= bexc && rank < bexc + s) {
      unsigned cum = bexc;
      for (int i = 0; i < per; i++) {
        unsigned cnt = loadAgent(&h[t * per + i]);
        if (rank < cum + cnt) {
          c->rank[j] = rank - cum;
          c->key[j] |= ((unsigned)(t * per + i)) << shift;
          break;
        }
        cum += cnt;
      }
    }
    __syncthreads();
  }
  if (finalize) {
    if (t == 0) {
      float v0 = keyToFloat(c->key[0]), v1 = keyToFloat(c->key[1]);
      float v2 = keyToFloat(c->key[2]), v3 = keyToFloat(c->key[3]);
      float plo = __fadd_rn(__fmul_rn(v0, lwlo), __fmul_rn(v1, hwlo));
      float phi = __fadd_rn(__fmul_rn(v2, lwhi), __fmul_rn(v3, hwhi));
      float am = fmaxf(fabsf(plo), fabsf(phi));
      float sc = (am > 0.0f) ? __fdiv_rn(127.0f, am) : 128.0f;
      c->scale = sc;
      base[0] = __float_as_uint(sc);
    }
    __syncthreads();
    if (t < 16) {
      float sc = __uint_as_float(base[0]);
      int u2 = (t << 4) | 9;
      int s = (u2 >= 128) ? u2 - 256 : u2;
      c->lut[t] = __fdiv_rn((float)s, sc);
    }
  }
}

// ============ conv1 (1->6, 5x5, pad2) + relu + pool ============
#define C1_IMGS 6
__global__ __launch_bounds__(256) void conv1_plain(
    const float* __restrict__ x, const float* __restrict__ w,
    const float* __restrict__ bias, float* __restrict__ act1) {
  __shared__ __align__(16) float img[C1_IMGS * 1032];  // 32x32 padded, stride 1032
  __shared__ float wl[150];
  __shared__ float bl[6];
  int t = threadIdx.x;
  long long b0 = (long long)blockIdx.x * C1_IMGS;
  if (t < 150) wl[t] = w[t];
  if (t < 6) bl[t] = bias[t];
  for (int i = t; i < C1_IMGS * 1032; i += 256) img[i] = 0.0f;
  __syncthreads();
  for (int idx = t; idx < C1_IMGS * 784; idx += 256) {
    int im = idx / 784, rem = idx % 784;
    int r = rem / 28, cc = rem % 28;
    long long bb = b0 + im;
    if (bb < NB) img[im * 1032 + (r + 2) * 32 + (cc + 2)] = x[bb * 784 + rem];
  }
  __syncthreads();
  int im = t / 42, rem2 = t % 42, cg = rem2 / 14, pc = rem2 % 14;
  if (im < C1_IMGS) {
    long long bb = b0 + im;
    if (bb < NB) {
      const float* ib = &img[im * 1032];
      float wa[25], wb[25];
#pragma unroll
      for (int k = 0; k < 25; k++) {
        wa[k] = wl[(2 * cg) * 25 + k];
        wb[k] = wl[(2 * cg + 1) * 25 + k];
      }
      float biasA = bl[2 * cg], biasB = bl[2 * cg + 1];
      float* oA = act1 + bb * 1176 + (2 * cg) * 196 + pc;
      float* oB = oA + 196;
      for (int pr = 0; pr < 14; pr++) {
        float rw[6][6];
        const float* rp = ib + (2 * pr) * 32 + 2 * pc;
#pragma unroll
        for (int rr = 0; rr < 6; rr++) {
#pragma unroll
          for (int k2 = 0; k2 < 3; k2++) {
            float2 f = *(const float2*)&rp[rr * 32 + 2 * k2];
            rw[rr][2 * k2] = f.x;
            rw[rr][2 * k2 + 1] = f.y;
          }
        }
        float a00 = 0.f, a01 = 0.f, a10 = 0.f, a11 = 0.f;
        float c00 = 0.f, c01 = 0.f, c10 = 0.f, c11 = 0.f;
#pragma unroll
        for (int i = 0; i < 5; i++) {
#pragma unroll
          for (int j = 0; j < 5; j++) {
            float wva = wa[i * 5 + j], wvb = wb[i * 5 + j];
            a00 = fmaf(rw[i][j], wva, a00);
            a01 = fmaf(rw[i][j + 1], wva, a01);
            a10 = fmaf(rw[i + 1][j], wva, a10);
            a11 = fmaf(rw[i + 1][j + 1], wva, a11);
            c00 = fmaf(rw[i][j], wvb, c00);
            c01 = fmaf(rw[i][j + 1], wvb, c01);
            c10 = fmaf(rw[i + 1][j], wvb, c10);
            c11 = fmaf(rw[i + 1][j + 1], wvb, c11);
          }
        }
        float ma = fmaxf(fmaxf(a00, a01), fmaxf(a10, a11));
        float mb = fmaxf(fmaxf(c00, c01), fmaxf(c10, c11));
        oA[pr * 14] = fmaxf(ma + biasA, 0.0f);
        oB[pr * 14] = fmaxf(mb + biasB, 0.0f);
      }
    }
  }
}

// ===== conv2 (6->16, 5x5 VALID) + LUT-dequant-on-load + relu + pool =====
#define C2_IMGS 10
__global__ __launch_bounds__(256, 2) void conv2_plain(
    const float* __restrict__ act1, const float* __restrict__ w,
    const float* __restrict__ bias, const Ctrl* __restrict__ cin,
    float* __restrict__ act2) {
  __shared__ __align__(16) float img[C2_IMGS * 1176];  // linear copy of 10 images
  __shared__ __align__(16) float wl[3840];             // [c][ci][ki][8] padded rows
  __shared__ float bl[16];
  __shared__ float lutS[16];
  int t = threadIdx.x;
  long long b0 = (long long)blockIdx.x * C2_IMGS;
  float scale = cin->scale;
  for (int idx = t; idx < 2400; idx += 256) {
    int c = idx / 150, rem = idx % 150;
    int ci = rem / 25, k = rem % 25;
    wl[((c * 6 + ci) * 5 + k / 5) * 8 + k % 5] = w[idx];
  }
  if (t < 16) { bl[t] = bias[t]; lutS[t] = cin->lut[t]; }
  __syncthreads();  // lutS ready before staging
  long long imgs = NB - b0;
  if (imgs > C2_IMGS) imgs = C2_IMGS;
  int nrem = (int)imgs * 1176;
  for (int idx = t; idx < C2_IMGS * 1176; idx += 256) {
    float v = 0.0f;
    if (idx < nrem) v = qmapLut(act1[b0 * 1176 + idx], scale, lutS);
    img[idx] = v;
  }
  __syncthreads();
  int im = t / 25, p = t % 25;  // t < 250 active
  if (im < C2_IMGS && b0 + im < NB) {
    long long bb = b0 + im;
    int pr = p / 5, pcol = p % 5;
    const float* ib = &img[im * 1176 + pr * 28 + 2 * pcol];
#pragma unroll
    for (int half = 0; half < 2; half++) {
      float acc[8][4];
#pragma unroll
      for (int cc = 0; cc < 8; cc++)
#pragma unroll
        for (int q = 0; q < 4; q++) acc[cc][q] = 0.f;
      for (int ci = 0; ci < 6; ci++) {
        float win[6][6];
        const float* rp = ib + ci * 196;
#pragma unroll
        for (int rr = 0; rr < 6; rr++) {
#pragma unroll
          for (int k2 = 0; k2 < 3; k2++) {
            float2 f = *(const float2*)&rp[rr * 14 + 2 * k2];
            win[rr][2 * k2] = f.x;
            win[rr][2 * k2 + 1] = f.y;
          }
        }
#pragma unroll
        for (int cc = 0; cc < 8; cc++) {
          int c = half * 8 + cc;
#pragma unroll
          for (int ki = 0; ki < 5; ki++) {
            const float* wr = &wl[((c * 6 + ci) * 5 + ki) * 8];
            float4 w0 = *(const float4*)wr;
            float wk[5] = {w0.x, w0.y, w0.z, w0.w, wr[4]};
#pragma unroll
            for (int kj = 0; kj < 5; kj++) {
              float wv = wk[kj];
              acc[cc][0] = fmaf(win[ki][kj], wv, acc[cc][0]);
              acc[cc][1] = fmaf(win[ki][kj + 1], wv, acc[cc][1]);
              acc[cc][2] = fmaf(win[ki + 1][kj], wv, acc[cc][2]);
              acc[cc][3] = fmaf(win[ki + 1][kj + 1], wv, acc[cc][3]);
            }
          }
        }
      }
#pragma unroll
      for (int cc = 0; cc < 8; cc++) {
        int c = half * 8 + cc;
        float m = fmaxf(fmaxf(acc[cc][0], acc[cc][1]), fmaxf(acc[cc][2], acc[cc][3]));
        act2[(bb * 16 + c) * 25 + p] = fmaxf(m + bl[c], 0.0f);
      }
    }
  }
}

// ============ L1 streaming histogram (4096 bins) + fused scan ============
__global__ __launch_bounds__(256) void hist1_fused(
    const float4* __restrict__ a, long long n4, unsigned* __restrict__ hist,
    unsigned* __restrict__ counter, Ctrl* ctrl,
    unsigned r0, unsigned r1, unsigned r2, unsigned r3) {
  __shared__ unsigned h[4096];
  __shared__ unsigned lastFlag;
  int t = threadIdx.x;
  for (int i = t; i < 4096; i += 256) h[i] = 0;
  __syncthreads();
  unsigned zc = 0;
  long long stride = (long long)gridDim.x * 256;
  for (long long i = (long long)blockIdx.x * 256 + t; i < n4; i += stride) {
    float4 v = a[i];
    float vals[4] = {v.x, v.y, v.z, v.w};
#pragma unroll
    for (int q = 0; q < 4; q++) {
      unsigned bits = __float_as_uint(vals[q]);
      if (bits == 0u) { zc++; continue; }
      atomicAdd(&h[keyOf(vals[q]) >> 20], 1u);
    }
  }
  if (zc) atomicAdd(&h[2048], zc);  // +0 bin
  __syncthreads();
  for (int i = t; i < 4096; i += 256) {
    unsigned v = h[i];
    if (v) atomicAdd(&hist[i], v);
  }
  __threadfence();
  if (t == 0) lastFlag = (atomicAdd(counter, 1u) == gridDim.x - 1);
  __syncthreads();
  if (lastFlag)
    scan_device(hist, 4096, 1, 20, ctrl, 1, r0, r1, r2, r3, 0, 0.f, 0.f, 0.f, 0.f, h);
}

// ============ sub-level histogram pass + fused scan (levels 2 and 3) ============
__global__ __launch_bounds__(256) void sub_fused(
    const float4* __restrict__ a, long long n4, Ctrl* c,
    unsigned* __restrict__ histOut, int level, unsigned* __restrict__ counter,
    int finalize, float lwlo, float hwlo, float lwhi, float hwhi) {
  __shared__ unsigned h[4096];
  __shared__ unsigned lastFlag;
  int t = threadIdx.x;
  for (int i = t; i < 4096; i += 256) h[i] = 0;
  __syncthreads();
  unsigned p0 = c->key[0], p1 = c->key[1], p2 = c->key[2], p3 = c->key[3];
  unsigned mask = (level == 2) ? 0xFFF00000u : 0xFFFFFC00u;
  int sh = (level == 2) ? 10 : 0;
  const unsigned zkey = 0x80000000u;
  int zm0 = ((zkey & mask) == p0), zm1 = ((zkey & mask) == p1);
  int zm2 = ((zkey & mask) == p2), zm3 = ((zkey & mask) == p3);
  unsigned zbin = (zkey >> sh) & 1023u;
  unsigned zc = 0;
  long long stride = (long long)gridDim.x * 256;
  for (long long i = (long long)blockIdx.x * 256 + t; i < n4; i += stride) {
    float4 v = a[i];
    float vals[4] = {v.x, v.y, v.z, v.w};
#pragma unroll
    for (int q = 0; q < 4; q++) {
      unsigned bits = __float_as_uint(vals[q]);
      if (bits == 0u) { zc++; continue; }
      unsigned k = keyOf(vals[q]);
      unsigned pf = k & mask;
      unsigned bin = (k >> sh) & 1023u;
      if (pf == p0) atomicAdd(&h[bin], 1u);
      if (pf == p1) atomicAdd(&h[1024 + bin], 1u);
      if (pf == p2) atomicAdd(&h[2048 + bin], 1u);
      if (pf == p3) atomicAdd(&h[3072 + bin], 1u);
    }
  }
  if (zc) {
    if (zm0) atomicAdd(&h[zbin], zc);
    if (zm1) atomicAdd(&h[1024 + zbin], zc);
    if (zm2) atomicAdd(&h[2048 + zbin], zc);
    if (zm3) atomicAdd(&h[3072 + zbin], zc);
  }
  __syncthreads();
  for (int i = t; i < 4096; i += 256) {
    unsigned v = h[i];
    if (v) atomicAdd(&histOut[i], v);
  }
  __threadfence();
  if (t == 0) lastFlag = (atomicAdd(counter, 1u) == gridDim.x - 1);
  __syncthreads();
  if (lastFlag)
    scan_device(histOut, 1024, 0, sh, c, 0, 0u, 0u, 0u, 0u, finalize, lwlo, hwlo, lwhi, hwhi, h);
}

// ============ fc1: [B,400] x [120,400]^T + LUT-dequant + relu ============
__global__ __launch_bounds__(256) void fc1_plain(
    const float* __restrict__ A, const float* __restrict__ W,
    const float* __restrict__ bias, const Ctrl* __restrict__ cin,
    float* __restrict__ out) {
  __shared__ float As[32][100];
  __shared__ float Ws[120][100];
  __shared__ float lutS[16];
  int t = threadIdx.x;
  size_t b0 = (size_t)blockIdx.x * 32;
  float scale = cin->scale;
  if (t < 16) lutS[t] = cin->lut[t];
  int ng = t & 7, bs = t >> 3;
  float acc[15];
#pragma unroll
  for (int i = 0; i < 15; i++) acc[i] = 0.f;
  for (int kc = 0; kc < 4; kc++) {
    __syncthreads();
    for (int idx = t; idx < 3200; idx += 256) {
      int row = idx / 100, k = idx % 100;
      As[row][k] = qmapLut(A[(b0 + row) * 400 + kc * 100 + k], scale, lutS);
    }
    for (int idx = t; idx < 12000; idx += 256) {
      int n = idx / 100, k = idx % 100;
      Ws[n][k] = W[n * 400 + kc * 100 + k];
    }
    __syncthreads();
    for (int k = 0; k < 100; k++) {
      float av = As[bs][k];
#pragma unroll
      for (int i = 0; i < 15; i++) acc[i] = fmaf(av, Ws[ng + 8 * i][k], acc[i]);
    }
  }
#pragma unroll
  for (int i = 0; i < 15; i++) {
    int n = ng + 8 * i;
    out[(b0 + bs) * 120 + n] = fmaxf(acc[i] + bias[n], 0.0f);
  }
}

// ============ fc2: [B,120] x [84,120]^T + LUT-dequant + relu ============
__global__ __launch_bounds__(256) void fc2_plain(
    const float* __restrict__ A, const float* __restrict__ W,
    const float* __restrict__ bias, const Ctrl* __restrict__ cin,
    float* __restrict__ out) {
  __shared__ float As[64][121];
  __shared__ float Ws[84][120];
  __shared__ float lutS[16];
  int t = threadIdx.x;
  size_t b0 = (size_t)blockIdx.x * 64;
  float scale = cin->scale;
  if (t < 16) lutS[t] = cin->lut[t];
  __syncthreads();  // lutS ready
  int ng = t & 3, bs = t >> 2;
  float acc[21];
#pragma unroll
  for (int i = 0; i < 21; i++) acc[i] = 0.f;
  for (int idx = t; idx < 7680; idx += 256) {
    int row = idx / 120, k = idx % 120;
    As[row][k] = qmapLut(A[(b0 + row) * 120 + k], scale, lutS);
  }
  for (int idx = t; idx < 10080; idx += 256) {
    int n = idx / 120, k = idx % 120;
    Ws[n][k] = W[n * 120 + k];
  }
  __syncthreads();
  for (int k = 0; k < 120; k++) {
    float av = As[bs][k];
#pragma unroll
    for (int i = 0; i < 21; i++) acc[i] = fmaf(av, Ws[ng + 4 * i][k], acc[i]);
  }
#pragma unroll
  for (int i = 0; i < 21; i++) {
    int n = ng + 4 * i;
    out[(b0 + bs) * 84 + n] = fmaxf(acc[i] + bias[n], 0.0f);
  }
}

// ============ fc3: [B,84] x [10,84]^T + LUT-dequant -> d_out ============
__global__ __launch_bounds__(256) void fc3_fused(
    const float* __restrict__ A, const float* __restrict__ W,
    const float* __restrict__ bias, const Ctrl* __restrict__ cin,
    float* __restrict__ out) {
  __shared__ float As[64][84];
  __shared__ float Ws[10][84];
  __shared__ float bl[10];
  __shared__ float lutS[16];
  int t = threadIdx.x;
  size_t b0 = (size_t)blockIdx.x * 64;
  float scale = cin->scale;
  if (t < 16) lutS[t] = cin->lut[t];
  __syncthreads();  // lutS ready
  int ng = t & 3, bs = t >> 2;
  for (int idx = t; idx < 5376; idx += 256) {
    int row = idx / 84, k = idx % 84;
    As[row][k] = qmapLut(A[(b0 + row) * 84 + k], scale, lutS);
  }
  for (int idx = t; idx < 840; idx += 256) Ws[idx / 84][idx % 84] = W[idx];
  if (t < 10) bl[t] = bias[t];
  __syncthreads();
  float acc[3] = {0.f, 0.f, 0.f};
  for (int k = 0; k < 84; k++) {
    float av = As[bs][k];
#pragma unroll
    for (int i = 0; i < 3; i++) {
      int n = ng + 4 * i;
      if (n < 10) acc[i] = fmaf(av, Ws[n][k], acc[i]);
    }
  }
#pragma unroll
  for (int i = 0; i < 3; i++) {
    int n = ng + 4 * i;
    if (n < 10) out[(b0 + bs) * 10 + n] = acc[i] + bl[n];
  }
}

// ---------------- host ----------------
static void qparams(long long n, unsigned r[4], float w[4]) {
  float nf = (float)n;
  float nm1 = nf - 1.0f;
  float qlo = 2.5f / 100.0f, qhi = 97.5f / 100.0f;
  float ilo = qlo * nm1;
  float flo = floorf(ilo), clo = ceilf(ilo);
  float hwlo = ilo - flo, lwlo = 1.0f - hwlo;
  float ihi = qhi * nm1;
  float fhi = floorf(ihi), chi = ceilf(ihi);
  float hwhi = ihi - fhi, lwhi = 1.0f - hwhi;
  if (flo < 0) flo = 0;
  if (clo < 0) clo = 0;
  if (fhi < 0) fhi = 0;
  if (chi < 0) chi = 0;
  unsigned nmax = (unsigned)(n - 1);
  r[0] = (unsigned)flo; if (r[0] > nmax) r[0] = nmax;
  r[1] = (unsigned)clo; if (r[1] > nmax) r[1] = nmax;
  r[2] = (unsigned)fhi; if (r[2] > nmax) r[2] = nmax;
  r[3] = (unsigned)chi; if (r[3] > nmax) r[3] = nmax;
  w[0] = lwlo; w[1] = hwlo; w[2] = lwhi; w[3] = hwhi;
}

extern "C" void kernel_launch(void* const* d_in, const int* in_sizes, int n_in,
                              void* d_out, int out_size, void* d_ws, size_t ws_size,
                              hipStream_t stream) {
  const float* x   = (const float*)d_in[0];
  const float* c1w = (const float*)d_in[1];
  const float* c1b = (const float*)d_in[2];
  const float* c2w = (const float*)d_in[3];
  const float* c2b = (const float*)d_in[4];
  const float* f1w = (const float*)d_in[5];
  const float* f1b = (const float*)d_in[6];
  const float* f2w = (const float*)d_in[7];
  const float* f2b = (const float*)d_in[8];
  const float* f3w = (const float*)d_in[9];
  const float* f3b = (const float*)d_in[10];
  float* outp = (float*)d_out;

  char* ws = (char*)d_ws;
  size_t off = 0;
  auto alloc = [&](size_t bytes) {
    void* p = ws + off;
    off += (bytes + 255) & ~(size_t)255;
    return p;
  };
  float* act1 = (float*)alloc((size_t)NB * 1176 * 4);
  float* act2 = (float*)alloc((size_t)NB * 400 * 4);
  size_t metaBytes = 4 * 12288 * 4 + 16 * 4 + 4 * sizeof(Ctrl);
  unsigned* meta = (unsigned*)alloc(metaBytes);
  unsigned* cnt = meta + 4 * 12288;
  Ctrl* ctrl = (Ctrl*)(cnt + 16);
  float* fc1o = act1;                     // reuse after conv2 consumed act1
  float* fc2o = act1 + (size_t)NB * 120;

  auto H = [&](int s, int lvl) {  // lvl 1,2,3
    return meta + s * 12288 + (lvl == 1 ? 0 : (lvl == 2 ? 4096 : 8192));
  };

  long long n1 = (long long)NB * 1176, n2 = (long long)NB * 400;
  long long n3 = (long long)NB * 120, n4n = (long long)NB * 84;
  unsigned r1[4], r2[4], r3[4], r4[4];
  float w1[4], w2[4], w3[4], w4[4];
  qparams(n1, r1, w1);
  qparams(n2, r2, w2);
  qparams(n3, r3, w3);
  qparams(n4n, r4, w4);

  hipMemsetAsync(meta, 0, metaBytes, stream);

  int g1 = (NB + C1_IMGS - 1) / C1_IMGS;  // 2731
  int g2 = (NB + C2_IMGS - 1) / C2_IMGS;  // 1639

  // stage 0: conv1 -> act1, percentile(act1)
  conv1_plain<<<g1, 256, 0, stream>>>(x, c1w, c1b, act1);
  hist1_fused<<<2048, 256, 0, stream>>>((const float4*)act1, n1 / 4, H(0, 1), &cnt[0],
                                        &ctrl[0], r1[0], r1[1], r1[2], r1[3]);
  sub_fused<<<2048, 256, 0, stream>>>((const float4*)act1, n1 / 4, &ctrl[0], H(0, 2), 2,
                                      &cnt[1], 0, 0.f, 0.f, 0.f, 0.f);
  sub_fused<<<2048, 256, 0, stream>>>((const float4*)act1, n1 / 4, &ctrl[0], H(0, 3), 3,
                                      &cnt[2], 1, w1[0], w1[1], w1[2], w1[3]);
  // stage 1: conv2 (dequant act1 on load) -> act2, percentile(act2)
  conv2_plain<<<g2, 256, 0, stream>>>(act1, c2w, c2b, &ctrl[0], act2);
  hist1_fused<<<1024, 256, 0, stream>>>((const float4*)act2, n2 / 4, H(1, 1), &cnt[3],
                                        &ctrl[1], r2[0], r2[1], r2[2], r2[3]);
  sub_fused<<<1024, 256, 0, stream>>>((const float4*)act2, n2 / 4, &ctrl[1], H(1, 2), 2,
                                      &cnt[4], 0, 0.f, 0.f, 0.f, 0.f);
  sub_fused<<<1024, 256, 0, stream>>>((const float4*)act2, n2 / 4, &ctrl[1], H(1, 3), 3,
                                      &cnt[5], 1, w2[0], w2[1], w2[2], w2[3]);
  // stage 2: fc1 (dequant act2 on load) -> fc1o, percentile(fc1o)
  fc1_plain<<<NB / 32, 256, 0, stream>>>(act2, f1w, f1b, &ctrl[1], fc1o);
  hist1_fused<<<512, 256, 0, stream>>>((const float4*)fc1o, n3 / 4, H(2, 1), &cnt[6],
                                       &ctrl[2], r3[0], r3[1], r3[2], r3[3]);
  sub_fused<<<512, 256, 0, stream>>>((const float4*)fc1o, n3 / 4, &ctrl[2], H(2, 2), 2,
                                     &cnt[7], 0, 0.f, 0.f, 0.f, 0.f);
  sub_fused<<<512, 256, 0, stream>>>((const float4*)fc1o, n3 / 4, &ctrl[2], H(2, 3), 3,
                                     &cnt[8], 1, w3[0], w3[1], w3[2], w3[3]);
  // stage 3: fc2 (dequant fc1o on load) -> fc2o, percentile(fc2o)
  fc2_plain<<<NB / 64, 256, 0, stream>>>(fc1o, f2w, f2b, &ctrl[2], fc2o);
  hist1_fused<<<512, 256, 0, stream>>>((const float4*)fc2o, n4n / 4, H(3, 1), &cnt[9],
                                       &ctrl[3], r4[0], r4[1], r4[2], r4[3]);
  sub_fused<<<512, 256, 0, stream>>>((const float4*)fc2o, n4n / 4, &ctrl[3], H(3, 2), 2,
                                     &cnt[10], 0, 0.f, 0.f, 0.f, 0.f);
  sub_fused<<<512, 256, 0, stream>>>((const float4*)fc2o, n4n / 4, &ctrl[3], H(3, 3), 3,
                                     &cnt[11], 1, w4[0], w4[1], w4[2], w4[3]);
  // stage 4: fc3 (dequant fc2o on load) -> out
  fc3_fused<<<NB / 64, 256, 0, stream>>>(fc2o, f3w, f3b, &ctrl[3], outp);
}

// Round 6
// 1423.570 us; speedup vs baseline: 1.4201x; 1.0072x over previous
//
#include <hip/hip_runtime.h>
#include <stdint.h>
#include <math.h>

#define NB 16384  // batch

struct Ctrl {
  unsigned rank[4];
  unsigned key[4];
  float scale;
  unsigned pad[7];
  float lut[16];  // lut[i] = dequant value for nibble-index i, exact __fdiv_rn
};
static_assert(sizeof(Ctrl) == 128, "ctrl size");

__device__ __forceinline__ unsigned keyOf(float x) {
  unsigned u = __float_as_uint(x);
  return (u & 0x80000000u) ? ~u : (u | 0x80000000u);
}
__device__ __forceinline__ float keyToFloat(unsigned k) {
  unsigned u = (k & 0x80000000u) ? (k ^ 0x80000000u) : ~k;
  return __uint_as_float(u);
}
// dequant via LUT: floor/clamp then pick one of 16 exact s/scale values
__device__ __forceinline__ float qmapLut(float x, float scale, const float* lutS) {
  float t = __fmul_rn(x, scale);
  t = floorf(t);
  t = fminf(fmaxf(t, -128.0f), 127.0f);
  int qi = (int)t;
  return lutS[(qi >> 4) & 15];
}
__device__ __forceinline__ unsigned loadAgent(const unsigned* p) {
  return __hip_atomic_load(p, __ATOMIC_RELAXED, __HIP_MEMORY_SCOPE_AGENT);
}

// Walks the (globally accumulated) histogram; refines rank/key for 4 targets.
// Called by all 256 threads of one block. base = scratch LDS (>=256 entries).
__device__ void scan_device(const unsigned* hist, int nbins, int sharedHist, int shift,
                            Ctrl* c, int first, unsigned r0, unsigned r1, unsigned r2,
                            unsigned r3, int finalize, float lwlo, float hwlo,
                            float lwhi, float hwhi, unsigned* base) {
  int t = threadIdx.x;
  unsigned rinit[4] = {r0, r1, r2, r3};
  int per = nbins / 256;
  for (int j = 0; j < 4; j++) {
    const unsigned* h = hist + (sharedHist ? 0 : j * nbins);
    unsigned s = 0;
    for (int i = 0; i < per; i++) s += loadAgent(&h[t * per + i]);
    base[t] = s;
    __syncthreads();
    if (t == 0) {
      unsigned acc = 0;
      for (int i = 0; i < 256; i++) { unsigned v = base[i]; base[i] = acc; acc += v; }
    }
    __syncthreads();
    unsigned rank = first ? rinit[j] : c->rank[j];
    unsigned bexc = base[t];
    if (rank >= bexc && rank < bexc + s) {
      unsigned cum = bexc;
      for (int i = 0; i < per; i++) {
        unsigned cnt = loadAgent(&h[t * per + i]);
        if (rank < cum + cnt) {
          c->rank[j] = rank - cum;
          c->key[j] |= ((unsigned)(t * per + i)) << shift;
          break;
        }
        cum += cnt;
      }
    }
    __syncthreads();
  }
  if (finalize) {
    if (t == 0) {
      float v0 = keyToFloat(c->key[0]), v1 = keyToFloat(c->key[1]);
      float v2 = keyToFloat(c->key[2]), v3 = keyToFloat(c->key[3]);
      float plo = __fadd_rn(__fmul_rn(v0, lwlo), __fmul_rn(v1, hwlo));
      float phi = __fadd_rn(__fmul_rn(v2, lwhi), __fmul_rn(v3, hwhi));
      float am = fmaxf(fabsf(plo), fabsf(phi));
      float sc = (am > 0.0f) ? __fdiv_rn(127.0f, am) : 128.0f;
      c->scale = sc;
      base[0] = __float_as_uint(sc);
    }
    __syncthreads();
    if (t < 16) {
      float sc = __uint_as_float(base[0]);
      int u2 = (t << 4) | 9;
      int s = (u2 >= 128) ? u2 - 256 : u2;
      c->lut[t] = __fdiv_rn((float)s, sc);
    }
  }
}

// ============ conv1 (1->6, 5x5, pad2) + relu + pool ============
#define C1_IMGS 6
__global__ __launch_bounds__(256) void conv1_plain(
    const float* __restrict__ x, const float* __restrict__ w,
    const float* __restrict__ bias, float* __restrict__ act1) {
  __shared__ __align__(16) float img[C1_IMGS * 1032];  // 32x32 padded, stride 1032
  __shared__ float wl[150];
  __shared__ float bl[6];
  int t = threadIdx.x;
  long long b0 = (long long)blockIdx.x * C1_IMGS;
  if (t < 150) wl[t] = w[t];
  if (t < 6) bl[t] = bias[t];
  for (int i = t; i < C1_IMGS * 1032; i += 256) img[i] = 0.0f;
  __syncthreads();
  for (int idx = t; idx < C1_IMGS * 784; idx += 256) {
    int im = idx / 784, rem = idx % 784;
    int r = rem / 28, cc = rem % 28;
    long long bb = b0 + im;
    if (bb < NB) img[im * 1032 + (r + 2) * 32 + (cc + 2)] = x[bb * 784 + rem];
  }
  __syncthreads();
  int im = t / 42, rem2 = t % 42, cg = rem2 / 14, pc = rem2 % 14;
  if (im < C1_IMGS) {
    long long bb = b0 + im;
    if (bb < NB) {
      const float* ib = &img[im * 1032];
      float wa[25], wb[25];
#pragma unroll
      for (int k = 0; k < 25; k++) {
        wa[k] = wl[(2 * cg) * 25 + k];
        wb[k] = wl[(2 * cg + 1) * 25 + k];
      }
      float biasA = bl[2 * cg], biasB = bl[2 * cg + 1];
      float* oA = act1 + bb * 1176 + (2 * cg) * 196 + pc;
      float* oB = oA + 196;
      for (int pr = 0; pr < 14; pr++) {
        float rw[6][6];
        const float* rp = ib + (2 * pr) * 32 + 2 * pc;
#pragma unroll
        for (int rr = 0; rr < 6; rr++) {
#pragma unroll
          for (int k2 = 0; k2 < 3; k2++) {
            float2 f = *(const float2*)&rp[rr * 32 + 2 * k2];
            rw[rr][2 * k2] = f.x;
            rw[rr][2 * k2 + 1] = f.y;
          }
        }
        float a00 = 0.f, a01 = 0.f, a10 = 0.f, a11 = 0.f;
        float c00 = 0.f, c01 = 0.f, c10 = 0.f, c11 = 0.f;
#pragma unroll
        for (int i = 0; i < 5; i++) {
#pragma unroll
          for (int j = 0; j < 5; j++) {
            float wva = wa[i * 5 + j], wvb = wb[i * 5 + j];
            a00 = fmaf(rw[i][j], wva, a00);
            a01 = fmaf(rw[i][j + 1], wva, a01);
            a10 = fmaf(rw[i + 1][j], wva, a10);
            a11 = fmaf(rw[i + 1][j + 1], wva, a11);
            c00 = fmaf(rw[i][j], wvb, c00);
            c01 = fmaf(rw[i][j + 1], wvb, c01);
            c10 = fmaf(rw[i + 1][j], wvb, c10);
            c11 = fmaf(rw[i + 1][j + 1], wvb, c11);
          }
        }
        float ma = fmaxf(fmaxf(a00, a01), fmaxf(a10, a11));
        float mb = fmaxf(fmaxf(c00, c01), fmaxf(c10, c11));
        oA[pr * 14] = fmaxf(ma + biasA, 0.0f);
        oB[pr * 14] = fmaxf(mb + biasB, 0.0f);
      }
    }
  }
}

// ===== conv2 (6->16, 5x5 VALID) + LUT-dequant-on-load + relu + pool =====
// 512 threads: thread = (image, channel-half, pool-point). 10 images/block.
// img stride 1178 (even -> float2 aligned; mod 32 = 26 -> bank spread).
#define C2_IMGS 10
#define C2_IST 1178
__global__ __launch_bounds__(512, 4) void conv2_512(
    const float* __restrict__ act1, const float* __restrict__ w,
    const float* __restrict__ bias, const Ctrl* __restrict__ cin,
    float* __restrict__ act2) {
  __shared__ __align__(16) float img[C2_IMGS * C2_IST];
  __shared__ __align__(16) float wl[3840];  // [c][ci][ki][8] padded rows
  __shared__ float bl[16];
  __shared__ float lutS[16];
  int t = threadIdx.x;
  long long b0 = (long long)blockIdx.x * C2_IMGS;
  float scale = cin->scale;
  for (int idx = t; idx < 2400; idx += 512) {
    int c = idx / 150, rem = idx % 150;
    int ci = rem / 25, k = rem % 25;
    wl[((c * 6 + ci) * 5 + k / 5) * 8 + k % 5] = w[idx];
  }
  if (t < 16) { bl[t] = bias[t]; lutS[t] = cin->lut[t]; }
  __syncthreads();  // lutS ready before staging
  long long imgs = NB - b0;
  if (imgs > C2_IMGS) imgs = C2_IMGS;
  int nrem = (int)imgs * 1176;
  for (int idx = t; idx < C2_IMGS * 1176; idx += 512) {
    float v = 0.0f;
    if (idx < nrem) v = qmapLut(act1[b0 * 1176 + idx], scale, lutS);
    img[(idx / 1176) * C2_IST + idx % 1176] = v;
  }
  __syncthreads();
  int im = t / 50, rem = t % 50, half = rem / 25, p = rem % 25;  // t < 500 active
  if (im < C2_IMGS && b0 + im < NB) {
    long long bb = b0 + im;
    int pr = p / 5, pcol = p % 5;
    const float* ib = &img[im * C2_IST + pr * 28 + 2 * pcol];
    float acc[8][4];
#pragma unroll
    for (int cc = 0; cc < 8; cc++)
#pragma unroll
      for (int q = 0; q < 4; q++) acc[cc][q] = 0.f;
    for (int ci = 0; ci < 6; ci++) {
      float win[6][6];
      const float* rp = ib + ci * 196;
#pragma unroll
      for (int rr = 0; rr < 6; rr++) {
#pragma unroll
        for (int k2 = 0; k2 < 3; k2++) {
          float2 f = *(const float2*)&rp[rr * 14 + 2 * k2];
          win[rr][2 * k2] = f.x;
          win[rr][2 * k2 + 1] = f.y;
        }
      }
#pragma unroll
      for (int cc = 0; cc < 8; cc++) {
        int c = half * 8 + cc;
#pragma unroll
        for (int ki = 0; ki < 5; ki++) {
          const float* wr = &wl[((c * 6 + ci) * 5 + ki) * 8];
          float4 w0 = *(const float4*)wr;
          float wk[5] = {w0.x, w0.y, w0.z, w0.w, wr[4]};
#pragma unroll
          for (int kj = 0; kj < 5; kj++) {
            float wv = wk[kj];
            acc[cc][0] = fmaf(win[ki][kj], wv, acc[cc][0]);
            acc[cc][1] = fmaf(win[ki][kj + 1], wv, acc[cc][1]);
            acc[cc][2] = fmaf(win[ki + 1][kj], wv, acc[cc][2]);
            acc[cc][3] = fmaf(win[ki + 1][kj + 1], wv, acc[cc][3]);
          }
        }
      }
    }
#pragma unroll
    for (int cc = 0; cc < 8; cc++) {
      int c = half * 8 + cc;
      float m = fmaxf(fmaxf(acc[cc][0], acc[cc][1]), fmaxf(acc[cc][2], acc[cc][3]));
      act2[(bb * 16 + c) * 25 + p] = fmaxf(m + bl[c], 0.0f);
    }
  }
}

// ===== L1 streaming histogram: 2048 nonneg bins, 4-way wave-privatized =====
__global__ __launch_bounds__(256) void hist1_fused(
    const float4* __restrict__ a, long long n4, unsigned* __restrict__ hist,
    unsigned* __restrict__ counter, Ctrl* ctrl,
    unsigned r0, unsigned r1, unsigned r2, unsigned r3) {
  __shared__ unsigned h[4 * 2048];  // 32 KB: one 2048-bin copy per wave
  __shared__ unsigned lastFlag;
  int t = threadIdx.x;
  for (int i = t; i < 8192; i += 256) h[i] = 0;
  __syncthreads();
  unsigned* hw = &h[(t >> 6) * 2048];
  unsigned zc = 0;
  long long stride = (long long)gridDim.x * 256;
  for (long long i = (long long)blockIdx.x * 256 + t; i < n4; i += stride) {
    float4 v = a[i];
    float vals[4] = {v.x, v.y, v.z, v.w};
#pragma unroll
    for (int q = 0; q < 4; q++) {
      unsigned bits = __float_as_uint(vals[q]);
      if ((bits << 1) == 0u) { zc++; continue; }  // +-0
      atomicAdd(&hw[(keyOf(vals[q]) >> 20) - 2048], 1u);
    }
  }
  if (zc) atomicAdd(&hw[0], zc);  // zero bin = key 2048
  __syncthreads();
  for (int i = t; i < 2048; i += 256) {
    unsigned v = h[i] + h[2048 + i] + h[4096 + i] + h[6144 + i];
    if (v) atomicAdd(&hist[2048 + i], v);
  }
  __threadfence();
  if (t == 0) lastFlag = (atomicAdd(counter, 1u) == gridDim.x - 1);
  __syncthreads();
  if (lastFlag)
    scan_device(hist, 4096, 1, 20, ctrl, 1, r0, r1, r2, r3, 0, 0.f, 0.f, 0.f, 0.f, h);
}

// ============ sub-level histogram pass + fused scan (levels 2 and 3) ============
__global__ __launch_bounds__(256) void sub_fused(
    const float4* __restrict__ a, long long n4, Ctrl* c,
    unsigned* __restrict__ histOut, int level, unsigned* __restrict__ counter,
    int finalize, float lwlo, float hwlo, float lwhi, float hwhi) {
  __shared__ unsigned h[4096];
  __shared__ unsigned lastFlag;
  int t = threadIdx.x;
  for (int i = t; i < 4096; i += 256) h[i] = 0;
  __syncthreads();
  unsigned p0 = c->key[0], p1 = c->key[1], p2 = c->key[2], p3 = c->key[3];
  unsigned mask = (level == 2) ? 0xFFF00000u : 0xFFFFFC00u;
  int sh = (level == 2) ? 10 : 0;
  const unsigned zkey = 0x80000000u;
  int zm0 = ((zkey & mask) == p0), zm1 = ((zkey & mask) == p1);
  int zm2 = ((zkey & mask) == p2), zm3 = ((zkey & mask) == p3);
  unsigned zbin = (zkey >> sh) & 1023u;
  unsigned zc = 0;
  long long stride = (long long)gridDim.x * 256;
  for (long long i = (long long)blockIdx.x * 256 + t; i < n4; i += stride) {
    float4 v = a[i];
    float vals[4] = {v.x, v.y, v.z, v.w};
#pragma unroll
    for (int q = 0; q < 4; q++) {
      unsigned bits = __float_as_uint(vals[q]);
      if (bits == 0u) { zc++; continue; }
      unsigned k = keyOf(vals[q]);
      unsigned pf = k & mask;
      unsigned bin = (k >> sh) & 1023u;
      if (pf == p0) atomicAdd(&h[bin], 1u);
      if (pf == p1) atomicAdd(&h[1024 + bin], 1u);
      if (pf == p2) atomicAdd(&h[2048 + bin], 1u);
      if (pf == p3) atomicAdd(&h[3072 + bin], 1u);
    }
  }
  if (zc) {
    if (zm0) atomicAdd(&h[zbin], zc);
    if (zm1) atomicAdd(&h[1024 + zbin], zc);
    if (zm2) atomicAdd(&h[2048 + zbin], zc);
    if (zm3) atomicAdd(&h[3072 + zbin], zc);
  }
  __syncthreads();
  for (int i = t; i < 4096; i += 256) {
    unsigned v = h[i];
    if (v) atomicAdd(&histOut[i], v);
  }
  __threadfence();
  if (t == 0) lastFlag = (atomicAdd(counter, 1u) == gridDim.x - 1);
  __syncthreads();
  if (lastFlag)
    scan_device(histOut, 1024, 0, sh, c, 0, 0u, 0u, 0u, 0u, finalize, lwlo, hwlo, lwhi, hwhi, h);
}

// ============ fc1: [B,400] x [120,400]^T + LUT-dequant + relu ============
__global__ __launch_bounds__(256) void fc1_plain(
    const float* __restrict__ A, const float* __restrict__ W,
    const float* __restrict__ bias, const Ctrl* __restrict__ cin,
    float* __restrict__ out) {
  __shared__ float As[32][100];
  __shared__ float Ws[120][100];
  __shared__ float lutS[16];
  int t = threadIdx.x;
  size_t b0 = (size_t)blockIdx.x * 32;
  float scale = cin->scale;
  if (t < 16) lutS[t] = cin->lut[t];
  int ng = t & 7, bs = t >> 3;
  float acc[15];
#pragma unroll
  for (int i = 0; i < 15; i++) acc[i] = 0.f;
  for (int kc = 0; kc < 4; kc++) {
    __syncthreads();
    for (int idx = t; idx < 3200; idx += 256) {
      int row = idx / 100, k = idx % 100;
      As[row][k] = qmapLut(A[(b0 + row) * 400 + kc * 100 + k], scale, lutS);
    }
    for (int idx = t; idx < 12000; idx += 256) {
      int n = idx / 100, k = idx % 100;
      Ws[n][k] = W[n * 400 + kc * 100 + k];
    }
    __syncthreads();
    for (int k = 0; k < 100; k++) {
      float av = As[bs][k];
#pragma unroll
      for (int i = 0; i < 15; i++) acc[i] = fmaf(av, Ws[ng + 8 * i][k], acc[i]);
    }
  }
#pragma unroll
  for (int i = 0; i < 15; i++) {
    int n = ng + 8 * i;
    out[(b0 + bs) * 120 + n] = fmaxf(acc[i] + bias[n], 0.0f);
  }
}

// ============ fc2: [B,120] x [84,120]^T + LUT-dequant + relu ============
__global__ __launch_bounds__(256) void fc2_plain(
    const float* __restrict__ A, const float* __restrict__ W,
    const float* __restrict__ bias, const Ctrl* __restrict__ cin,
    float* __restrict__ out) {
  __shared__ float As[64][121];
  __shared__ float Ws[84][120];
  __shared__ float lutS[16];
  int t = threadIdx.x;
  size_t b0 = (size_t)blockIdx.x * 64;
  float scale = cin->scale;
  if (t < 16) lutS[t] = cin->lut[t];
  __syncthreads();  // lutS ready
  int ng = t & 3, bs = t >> 2;
  float acc[21];
#pragma unroll
  for (int i = 0; i < 21; i++) acc[i] = 0.f;
  for (int idx = t; idx < 7680; idx += 256) {
    int row = idx / 120, k = idx % 120;
    As[row][k] = qmapLut(A[(b0 + row) * 120 + k], scale, lutS);
  }
  for (int idx = t; idx < 10080; idx += 256) {
    int n = idx / 120, k = idx % 120;
    Ws[n][k] = W[n * 120 + k];
  }
  __syncthreads();
  for (int k = 0; k < 120; k++) {
    float av = As[bs][k];
#pragma unroll
    for (int i = 0; i < 21; i++) acc[i] = fmaf(av, Ws[ng + 4 * i][k], acc[i]);
  }
#pragma unroll
  for (int i = 0; i < 21; i++) {
    int n = ng + 4 * i;
    out[(b0 + bs) * 84 + n] = fmaxf(acc[i] + bias[n], 0.0f);
  }
}

// ============ fc3: [B,84] x [10,84]^T + LUT-dequant -> d_out ============
__global__ __launch_bounds__(256) void fc3_fused(
    const float* __restrict__ A, const float* __restrict__ W,
    const float* __restrict__ bias, const Ctrl* __restrict__ cin,
    float* __restrict__ out) {
  __shared__ float As[64][84];
  __shared__ float Ws[10][84];
  __shared__ float bl[10];
  __shared__ float lutS[16];
  int t = threadIdx.x;
  size_t b0 = (size_t)blockIdx.x * 64;
  float scale = cin->scale;
  if (t < 16) lutS[t] = cin->lut[t];
  __syncthreads();  // lutS ready
  int ng = t & 3, bs = t >> 2;
  for (int idx = t; idx < 5376; idx += 256) {
    int row = idx / 84, k = idx % 84;
    As[row][k] = qmapLut(A[(b0 + row) * 84 + k], scale, lutS);
  }
  for (int idx = t; idx < 840; idx += 256) Ws[idx / 84][idx % 84] = W[idx];
  if (t < 10) bl[t] = bias[t];
  __syncthreads();
  float acc[3] = {0.f, 0.f, 0.f};
  for (int k = 0; k < 84; k++) {
    float av = As[bs][k];
#pragma unroll
    for (int i = 0; i < 3; i++) {
      int n = ng + 4 * i;
      if (n < 10) acc[i] = fmaf(av, Ws[n][k], acc[i]);
    }
  }
#pragma unroll
  for (int i = 0; i < 3; i++) {
    int n = ng + 4 * i;
    if (n < 10) out[(b0 + bs) * 10 + n] = acc[i] + bl[n];
  }
}

// ---------------- host ----------------
static void qparams(long long n, unsigned r[4], float w[4]) {
  float nf = (float)n;
  float nm1 = nf - 1.0f;
  float qlo = 2.5f / 100.0f, qhi = 97.5f / 100.0f;
  float ilo = qlo * nm1;
  float flo = floorf(ilo), clo = ceilf(ilo);
  float hwlo = ilo - flo, lwlo = 1.0f - hwlo;
  float ihi = qhi * nm1;
  float fhi = floorf(ihi), chi = ceilf(ihi);
  float hwhi = ihi - fhi, lwhi = 1.0f - hwhi;
  if (flo < 0) flo = 0;
  if (clo < 0) clo = 0;
  if (fhi < 0) fhi = 0;
  if (chi < 0) chi = 0;
  unsigned nmax = (unsigned)(n - 1);
  r[0] = (unsigned)flo; if (r[0] > nmax) r[0] = nmax;
  r[1] = (unsigned)clo; if (r[1] > nmax) r[1] = nmax;
  r[2] = (unsigned)fhi; if (r[2] > nmax) r[2] = nmax;
  r[3] = (unsigned)chi; if (r[3] > nmax) r[3] = nmax;
  w[0] = lwlo; w[1] = hwlo; w[2] = lwhi; w[3] = hwhi;
}

extern "C" void kernel_launch(void* const* d_in, const int* in_sizes, int n_in,
                              void* d_out, int out_size, void* d_ws, size_t ws_size,
                              hipStream_t stream) {
  const float* x   = (const float*)d_in[0];
  const float* c1w = (const float*)d_in[1];
  const float* c1b = (const float*)d_in[2];
  const float* c2w = (const float*)d_in[3];
  const float* c2b = (const float*)d_in[4];
  const float* f1w = (const float*)d_in[5];
  const float* f1b = (const float*)d_in[6];
  const float* f2w = (const float*)d_in[7];
  const float* f2b = (const float*)d_in[8];
  const float* f3w = (const float*)d_in[9];
  const float* f3b = (const float*)d_in[10];
  float* outp = (float*)d_out;

  char* ws = (char*)d_ws;
  size_t off = 0;
  auto alloc = [&](size_t bytes) {
    void* p = ws + off;
    off += (bytes + 255) & ~(size_t)255;
    return p;
  };
  float* act1 = (float*)alloc((size_t)NB * 1176 * 4);
  float* act2 = (float*)alloc((size_t)NB * 400 * 4);
  size_t metaBytes = 4 * 12288 * 4 + 16 * 4 + 4 * sizeof(Ctrl);
  unsigned* meta = (unsigned*)alloc(metaBytes);
  unsigned* cnt = meta + 4 * 12288;
  Ctrl* ctrl = (Ctrl*)(cnt + 16);
  float* fc1o = act1;                     // reuse after conv2 consumed act1
  float* fc2o = act1 + (size_t)NB * 120;

  auto H = [&](int s, int lvl) {  // lvl 1,2,3
    return meta + s * 12288 + (lvl == 1 ? 0 : (lvl == 2 ? 4096 : 8192));
  };

  long long n1 = (long long)NB * 1176, n2 = (long long)NB * 400;
  long long n3 = (long long)NB * 120, n4n = (long long)NB * 84;
  unsigned r1[4], r2[4], r3[4], r4[4];
  float w1[4], w2[4], w3[4], w4[4];
  qparams(n1, r1, w1);
  qparams(n2, r2, w2);
  qparams(n3, r3, w3);
  qparams(n4n, r4, w4);

  hipMemsetAsync(meta, 0, metaBytes, stream);

  int g1 = (NB + C1_IMGS - 1) / C1_IMGS;  // 2731
  int g2 = (NB + C2_IMGS - 1) / C2_IMGS;  // 1639

  // stage 0: conv1 -> act1, percentile(act1)
  conv1_plain<<<g1, 256, 0, stream>>>(x, c1w, c1b, act1);
  hist1_fused<<<2048, 256, 0, stream>>>((const float4*)act1, n1 / 4, H(0, 1), &cnt[0],
                                        &ctrl[0], r1[0], r1[1], r1[2], r1[3]);
  sub_fused<<<2048, 256, 0, stream>>>((const float4*)act1, n1 / 4, &ctrl[0], H(0, 2), 2,
                                      &cnt[1], 0, 0.f, 0.f, 0.f, 0.f);
  sub_fused<<<2048, 256, 0, stream>>>((const float4*)act1, n1 / 4, &ctrl[0], H(0, 3), 3,
                                      &cnt[2], 1, w1[0], w1[1], w1[2], w1[3]);
  // stage 1: conv2 (dequant act1 on load) -> act2, percentile(act2)
  conv2_512<<<g2, 512, 0, stream>>>(act1, c2w, c2b, &ctrl[0], act2);
  hist1_fused<<<1024, 256, 0, stream>>>((const float4*)act2, n2 / 4, H(1, 1), &cnt[3],
                                        &ctrl[1], r2[0], r2[1], r2[2], r2[3]);
  sub_fused<<<1024, 256, 0, stream>>>((const float4*)act2, n2 / 4, &ctrl[1], H(1, 2), 2,
                                      &cnt[4], 0, 0.f, 0.f, 0.f, 0.f);
  sub_fused<<<1024, 256, 0, stream>>>((const float4*)act2, n2 / 4, &ctrl[1], H(1, 3), 3,
                                      &cnt[5], 1, w2[0], w2[1], w2[2], w2[3]);
  // stage 2: fc1 (dequant act2 on load) -> fc1o, percentile(fc1o)
  fc1_plain<<<NB / 32, 256, 0, stream>>>(act2, f1w, f1b, &ctrl[1], fc1o);
  hist1_fused<<<512, 256, 0, stream>>>((const float4*)fc1o, n3 / 4, H(2, 1), &cnt[6],
                                       &ctrl[2], r3[0], r3[1], r3[2], r3[3]);
  sub_fused<<<512, 256, 0, stream>>>((const float4*)fc1o, n3 / 4, &ctrl[2], H(2, 2), 2,
                                     &cnt[7], 0, 0.f, 0.f, 0.f, 0.f);
  sub_fused<<<512, 256, 0, stream>>>((const float4*)fc1o, n3 / 4, &ctrl[2], H(2, 3), 3,
                                     &cnt[8], 1, w3[0], w3[1], w3[2], w3[3]);
  // stage 3: fc2 (dequant fc1o on load) -> fc2o, percentile(fc2o)
  fc2_plain<<<NB / 64, 256, 0, stream>>>(fc1o, f2w, f2b, &ctrl[2], fc2o);
  hist1_fused<<<512, 256, 0, stream>>>((const float4*)fc2o, n4n / 4, H(3, 1), &cnt[9],
                                       &ctrl[3], r4[0], r4[1], r4[2], r4[3]);
  sub_fused<<<512, 256, 0, stream>>>((const float4*)fc2o, n4n / 4, &ctrl[3], H(3, 2), 2,
                                     &cnt[10], 0, 0.f, 0.f, 0.f, 0.f);
  sub_fused<<<512, 256, 0, stream>>>((const float4*)fc2o, n4n / 4, &ctrl[3], H(3, 3), 3,
                                     &cnt[11], 1, w4[0], w4[1], w4[2], w4[3]);
  // stage 4: fc3 (dequant fc2o on load) -> out
  fc3_fused<<<NB / 64, 256, 0, stream>>>(fc2o, f3w, f3b, &ctrl[3], outp);
}